// Round 4
// baseline (202.486 us; speedup 1.0000x reference)
//
#include <hip/hip_runtime.h>
#include <math.h>

#define B_ 64
#define T_ 256
#define K_ 128
#define S_ 8
#define SEG_ 32

typedef float f32x4 __attribute__((ext_vector_type(4)));
typedef short bf16x8 __attribute__((ext_vector_type(8)));

static __device__ __forceinline__ unsigned int bf16rne(float x) {
    unsigned int u = __builtin_bit_cast(unsigned int, x);
    return (u + 0x7FFFu + ((u >> 16) & 1u)) >> 16;
}
static __device__ __forceinline__ unsigned int pkbf16(float a, float b) {
    return bf16rne(a) | (bf16rne(b) << 16);
}

// ---------------------------------------------------------------------------
// Phase 1: per-(batch,segment) transfer matrix M_s = prod diag(ey_t)*Texp.
// Wave w owns COLUMNS [32w,32w+32): column blocks evolve independently =>
// wave-private LDS, NO barriers in the main loop. A = full Texp in registers
// (128 VGPRs) -- REQUIRES the 256-VGPR budget, so occupancy is pinned with
// amdgpu_waves_per_eu(2,2) (LDS caps us at 2 blocks/CU anyway).
// Per step per wave: 8 ds_read_b128 (own 8KB block), 64 MFMA, 16 ds_write_b64.
// Renorm every 4 steps, wave-local shfl reduce, log-scale -> Cout[bs][w].
// LDS block layout: element (g,lc,j) at byte ((g*32+lc)*8+j)*2,
//   g=0..15 (rows 8g..8g+8), lc=0..31 (local col), j=0..7.
// NOTE: bf16 packing is the software RNE pkbf16 (R2-proven). The
// v_cvt_pk_bf16_f32 inline-asm variant produced NaNs (R3) -- do not reintroduce.
// ---------------------------------------------------------------------------
__global__ __launch_bounds__(256)
__attribute__((amdgpu_waves_per_eu(2, 2)))
void crf_seg_kernel(
    const float* __restrict__ y,
    const float* __restrict__ mask,
    const float* __restrict__ trans,
    unsigned short* __restrict__ Mout,   // [B*S][128 col][128 row] bf16
    float* __restrict__ Cout)            // [B*S][4] per-wave log-scales
{
    const int bs   = blockIdx.x;
    const int b    = bs >> 3;
    const int s    = bs & 7;
    const int tid  = threadIdx.x;
    const int w    = tid >> 6;
    const int lane = tid & 63;
    const int q    = lane >> 4;
    const int ci   = lane & 15;

    __shared__ __align__(16) unsigned short Mb[4][2][4096];  // 64 KB, per-wave dbuf
    __shared__ int lenS[4];

    // ---- sequence length (mask is a contiguous 1.0 prefix) ----
    {
        float mval = mask[b * T_ + tid];
        unsigned long long bal = __ballot(mval != 0.0f);
        if (lane == 0) lenS[w] = __popcll(bal);
    }

    // ---- identity columns [32w,32w+32) into buf 0 (wave-private) ----
    #pragma unroll
    for (int p = 0; p < 8; ++p) {
        const int idx = p * 64 + lane;       // 0..511 -> (g,lc)
        const int g   = idx >> 5;
        const int lc  = idx & 31;
        const int d   = 32 * w + lc - 8 * g; // 1.0 at row 8g+j == col 32w+lc
        uint4 u4 = make_uint4(0u, 0u, 0u, 0u);
        if (d >= 0 && d < 8)
            ((unsigned int*)&u4)[d >> 1] = (d & 1) ? 0x3F800000u : 0x00003F80u;
        *(uint4*)((char*)&Mb[w][0][0] + (g * 32 + lc) * 16) = u4;
    }

    // ---- A-frags: FULL Texp, rows 16mt+ci, A[m=ci][k=8q+j] (proven layout) ----
    bf16x8 A[8][4];
    #pragma unroll
    for (int mt = 0; mt < 8; ++mt) {
        const float* tp = trans + (16 * mt + ci) * K_;
        #pragma unroll
        for (int kt = 0; kt < 4; ++kt) {
            f32x4 pv = *(const f32x4*)(tp + 32 * kt + 8 * q);
            f32x4 rv = *(const f32x4*)(tp + 32 * kt + 8 * q + 4);
            uint4 u = make_uint4(pkbf16(__expf(pv.x), __expf(pv.y)),
                                 pkbf16(__expf(pv.z), __expf(pv.w)),
                                 pkbf16(__expf(rv.x), __expf(rv.y)),
                                 pkbf16(__expf(rv.z), __expf(rv.w)));
            A[mt][kt] = __builtin_bit_cast(bf16x8, u);
        }
    }

    __syncthreads();                         // lenS only; last barrier in kernel
    const int L = lenS[0] + lenS[1] + lenS[2] + lenS[3];
    int ns = L - SEG_ * s;
    ns = ns < 0 ? 0 : (ns > SEG_ ? SEG_ : ns);

    const float* yb = y + ((size_t)b * T_ + (size_t)SEG_ * s) * K_;

    float c_acc = 0.0f;
    float spart = 0.0f;
    int cur = 0;

    for (int tt = 0; tt < ns; ++tt) {
        // B-frags from own block: (kt,nt): rows 32kt+8q+j, col 16nt+ci
        const char* rb = (const char*)&Mb[w][cur][0];
        bf16x8 Bf[4][2];
        #pragma unroll
        for (int kt = 0; kt < 4; ++kt) {
            #pragma unroll
            for (int nt = 0; nt < 2; ++nt)
                Bf[kt][nt] = *(const bf16x8*)(rb + ((kt * 4 + q) * 32 + 16 * nt + ci) * 16);
        }

        // renorm: consume partial published at tt-1 (wave-local)
        float rinv = 1.0f;
        if (tt && (tt & 3) == 0) {
            float S = spart;
            S += __shfl_xor(S, 1);  S += __shfl_xor(S, 2);
            S += __shfl_xor(S, 4);  S += __shfl_xor(S, 8);
            S += __shfl_xor(S, 16); S += __shfl_xor(S, 32);
            rinv = __builtin_amdgcn_rcpf(S);
            c_acc += __logf(S);
            spart = 0.0f;
        }
        const bool pub = ((tt & 3) == 3);
        const float* yt = yb + tt * K_;

        char* wb = (char*)&Mb[w][cur ^ 1][0];
        #pragma unroll
        for (int mt = 0; mt < 8; ++mt) {
            f32x4 yv = *(const f32x4*)(yt + 16 * mt + 4 * q);  // L1-hit broadcast
            f32x4 C0 = {0.f, 0.f, 0.f, 0.f}, C1 = {0.f, 0.f, 0.f, 0.f};
            __builtin_amdgcn_s_setprio(1);
            #pragma unroll
            for (int kt = 0; kt < 4; ++kt) {
                C0 = __builtin_amdgcn_mfma_f32_16x16x32_bf16(A[mt][kt], Bf[kt][0], C0, 0, 0, 0);
                C1 = __builtin_amdgcn_mfma_f32_16x16x32_bf16(A[mt][kt], Bf[kt][1], C1, 0, 0, 0);
            }
            __builtin_amdgcn_s_setprio(0);
            f32x4 e;
            e.x = __expf(yv.x) * rinv; e.y = __expf(yv.y) * rinv;
            e.z = __expf(yv.z) * rinv; e.w = __expf(yv.w) * rinv;
            C0 *= e; C1 *= e;
            if (pub)
                spart += (C0.x + C0.y) + (C0.z + C0.w)
                       + (C1.x + C1.y) + (C1.z + C1.w);
            // write rows 16mt+4q+r, cols 16nt+ci -> g'=2mt+(q>>1), j'=4(q&1)+r
            const int gp = 2 * mt + (q >> 1);
            const int bo = 8 * (q & 1);
            uint2 d0 = make_uint2(pkbf16(C0.x, C0.y), pkbf16(C0.z, C0.w));
            uint2 d1 = make_uint2(pkbf16(C1.x, C1.y), pkbf16(C1.z, C1.w));
            *(uint2*)(wb + (gp * 32 + ci) * 16 + bo)      = d0;
            *(uint2*)(wb + (gp * 32 + 16 + ci) * 16 + bo) = d1;
        }
        cur ^= 1;
    }

    // ---- epilogue: own columns -> global [c][i] (coalesced 256B per 16 lanes)
    unsigned short* gout = Mout + ((size_t)bs << 14);
    const char* rb = (const char*)&Mb[w][cur][0];
    #pragma unroll
    for (int p = 0; p < 8; ++p) {
        const int lc = 4 * p + (lane >> 4);
        const int g  = lane & 15;
        uint4 v4 = *(const uint4*)(rb + (g * 32 + lc) * 16);
        *(uint4*)((char*)gout + (((32 * w + lc) << 7) + 8 * g) * 2) = v4;
    }
    if (lane == 0) Cout[bs * 4 + w] = c_acc;
}

// ---------------------------------------------------------------------------
// Phase 2: combine. One block per batch. Thread (cg,ig) owns c in [8cg,8cg+8),
// i in [8ig,8ig+8). Matrix chunks prefetched from global into ping-pong reg
// banks (static indexing), vectorized bf16 unpack + FMA, two-pass LDS reduce.
// Per-wave column-block scales folded into u before each matvec.
// ---------------------------------------------------------------------------
__global__ __launch_bounds__(256) void crf_comb_kernel(
    const unsigned short* __restrict__ Mseg,
    const float* __restrict__ Cseg,      // [B*S][4]
    float* __restrict__ out)
{
    const int b   = blockIdx.x;
    const int tid = threadIdx.x;
    const int cg  = tid >> 4;
    const int ig  = tid & 15;

    __shared__ float uSc[K_];
    __shared__ __align__(16) float tmp[16][K_];
    __shared__ float redS[4];

    if (tid < K_) uSc[tid] = (tid == 2) ? 1.0f : 0.0f;   // e_SOS

    float c_tot = 0.0f;
    uint4 RA[8], RB[8];
    {
        const unsigned short* M0 = Mseg + ((size_t)(b * S_) << 14);
        #pragma unroll
        for (int r = 0; r < 8; ++r)
            RA[r] = *(const uint4*)(M0 + ((8 * cg + r) << 7) + 8 * ig);
    }
    __syncthreads();

    #pragma unroll
    for (int s = 0; s < S_; ++s) {
        const uint4* Rcur = (s & 1) ? RB : RA;           // s is compile-time
        uint4*       Rnxt = (s & 1) ? RA : RB;
        if (s + 1 < S_) {
            const unsigned short* Mn = Mseg + ((size_t)(b * S_ + s + 1) << 14);
            #pragma unroll
            for (int r = 0; r < 8; ++r)
                Rnxt[r] = *(const uint4*)(Mn + ((8 * cg + r) << 7) + 8 * ig);
        }

        const float g0 = Cseg[(b * S_ + s) * 4 + 0];
        const float g1 = Cseg[(b * S_ + s) * 4 + 1];
        const float g2 = Cseg[(b * S_ + s) * 4 + 2];
        const float g3 = Cseg[(b * S_ + s) * 4 + 3];
        const float cmax = fmaxf(fmaxf(g0, g1), fmaxf(g2, g3));
        const float gw = (cg < 8) ? ((cg < 4) ? g0 : g1) : ((cg < 12) ? g2 : g3);
        const float fw = __expf(gw - cmax);

        float acc[8];
        #pragma unroll
        for (int e = 0; e < 8; ++e) acc[e] = 0.0f;
        #pragma unroll
        for (int r = 0; r < 8; ++r) {
            const float ub = uSc[8 * cg + r] * fw;
            const uint4 m4 = Rcur[r];
            const unsigned int* mw_ = (const unsigned int*)&m4;
            #pragma unroll
            for (int h2 = 0; h2 < 4; ++h2) {
                const unsigned int u = mw_[h2];
                acc[2 * h2]     += __builtin_bit_cast(float, u << 16) * ub;
                acc[2 * h2 + 1] += __builtin_bit_cast(float, u & 0xFFFF0000u) * ub;
            }
        }
        *(f32x4*)&tmp[cg][8 * ig]     = *(const f32x4*)&acc[0];
        *(f32x4*)&tmp[cg][8 * ig + 4] = *(const f32x4*)&acc[4];
        __syncthreads();

        float un = 0.0f;
        if (tid < K_) {
            #pragma unroll
            for (int c2 = 0; c2 < 16; ++c2) un += tmp[c2][tid];
        }
        float ps = un;
        ps += __shfl_xor(ps, 1);  ps += __shfl_xor(ps, 2);
        ps += __shfl_xor(ps, 4);  ps += __shfl_xor(ps, 8);
        ps += __shfl_xor(ps, 16); ps += __shfl_xor(ps, 32);
        if ((tid & 63) == 0) redS[tid >> 6] = ps;
        __syncthreads();
        const float total = (redS[0] + redS[1]) + (redS[2] + redS[3]);
        const float rt = 1.0f / total;
        if (tid < K_) uSc[tid] = un * rt;
        c_tot += __logf(total) + cmax;
        __syncthreads();
    }

    if (tid == 0) out[b] = c_tot;
}

extern "C" void kernel_launch(void* const* d_in, const int* in_sizes, int n_in,
                              void* d_out, int out_size, void* d_ws, size_t ws_size,
                              hipStream_t stream) {
    const float* y     = (const float*)d_in[0];   // (B, T, K) fp32
    const float* mask  = (const float*)d_in[1];   // (B, T)    fp32 0/1
    const float* trans = (const float*)d_in[2];   // (K, K)    fp32
    float* out = (float*)d_out;                   // (B,)      fp32

    unsigned short* Mws = (unsigned short*)d_ws;                       // 16.78 MB
    float* Cws = (float*)((char*)d_ws + (size_t)B_ * S_ * K_ * K_ * 2);

    crf_seg_kernel<<<B_ * S_, 256, 0, stream>>>(y, mask, trans, Mws, Cws);
    crf_comb_kernel<<<B_, 256, 0, stream>>>(Mws, Cws, out);
}

// Round 5
// 193.494 us; speedup vs baseline: 1.0465x; 1.0465x over previous
//
#include <hip/hip_runtime.h>
#include <math.h>

#define B_ 64
#define T_ 256
#define K_ 128
#define S_ 8
#define SEG_ 32

typedef float f32x4 __attribute__((ext_vector_type(4)));
typedef short bf16x8 __attribute__((ext_vector_type(8)));

static __device__ __forceinline__ unsigned int bf16rne(float x) {
    unsigned int u = __builtin_bit_cast(unsigned int, x);
    return (u + 0x7FFFu + ((u >> 16) & 1u)) >> 16;
}
static __device__ __forceinline__ unsigned int pkbf16(float a, float b) {
    return bf16rne(a) | (bf16rne(b) << 16);
}

// ---------------------------------------------------------------------------
// Phase 1: per-(batch,segment) transfer matrix M_s = prod diag(ey_t)*Texp.
// 512 threads = 8 waves. Wave (e=w>>2, u=w&3) computes output ROWS
// [64e,64e+64) of column block u (cols [32u,32u+32)). A = half of Texp in
// registers (A[4][4] = 64 VGPRs -> total fits the 128-VGPR budget, giving
// 4 waves/SIMD at 2 blocks/CU; the R2-R4 full-Texp variant needed 256 VGPRs,
// was capped at 128, and paid spill/AGPR-copy traffic every step).
// Pair (0,u),(1,u) shares LDS block Mb[u]: each writes its row half, both
// read all rows next step. One __syncthreads per step. y row staged to LDS
// (pre-exp'd) with issue-early/write-late split. Renorm every 4 steps via
// pair-summed partials in LDS; per-col-block log-scale -> Cout[bs][u].
// LDS block layout (R2-proven): element (g,lc,j) at byte (g*32+lc)*16 + 2j,
//   g=0..15 (rows 8g..8g+8), lc=0..31 (local col), j=0..7.
// bf16 pack = software RNE pkbf16 (R2-proven; inline-asm cvt_pk NaN'd in R3).
// ---------------------------------------------------------------------------
__global__ __launch_bounds__(512) void crf_seg_kernel(
    const float* __restrict__ y,
    const float* __restrict__ mask,
    const float* __restrict__ trans,
    unsigned short* __restrict__ Mout,   // [B*S][128 col][128 row] bf16
    float* __restrict__ Cout)            // [B*S][4] per-col-block log-scales
{
    const int bs   = blockIdx.x;
    const int b    = bs >> 3;
    const int s    = bs & 7;
    const int tid  = threadIdx.x;
    const int w    = tid >> 6;
    const int e    = w >> 2;        // row half 0/1
    const int u    = w & 3;         // column block 0..3
    const int lane = tid & 63;
    const int q    = lane >> 4;
    const int ci   = lane & 15;

    __shared__ __align__(16) unsigned short Mb[4][2][4096];  // 64 KB dbuf per u
    __shared__ __align__(16) float yS[2][K_];                // staged exp(y) rows
    __shared__ float wsumS[4][2];
    __shared__ int lenS[4];

    // ---- sequence length (mask is a contiguous 1.0 prefix; waves 0-3) ----
    if (tid < 256) {
        float mval = mask[b * T_ + tid];
        unsigned long long bal = __ballot(mval != 0.0f);
        if (lane == 0) lenS[w] = __popcll(bal);
    }

    // ---- identity: rows [64e,64e+64) of cols [32u,32u+32) into buf 0 ----
    #pragma unroll
    for (int p = 0; p < 4; ++p) {
        const int idx = p * 64 + lane;          // 0..255 -> (g,lc) in own half
        const int g   = 8 * e + (idx >> 5);
        const int lc  = idx & 31;
        const int d   = 32 * u + lc - 8 * g;    // 1.0 where row 8g+j == col
        uint4 u4 = make_uint4(0u, 0u, 0u, 0u);
        if (d >= 0 && d < 8)
            ((unsigned int*)&u4)[d >> 1] = (d & 1) ? 0x3F800000u : 0x00003F80u;
        *(uint4*)((char*)&Mb[u][0][0] + (g * 32 + lc) * 16) = u4;
    }

    // ---- A-frags: Texp rows [64e,64e+64): rows 64e+16mt+ci, A[m=ci][k=8q+j]
    bf16x8 A[4][4];
    #pragma unroll
    for (int mt = 0; mt < 4; ++mt) {
        const float* tp = trans + (64 * e + 16 * mt + ci) * K_;
        #pragma unroll
        for (int kt = 0; kt < 4; ++kt) {
            f32x4 pv = *(const f32x4*)(tp + 32 * kt + 8 * q);
            f32x4 rv = *(const f32x4*)(tp + 32 * kt + 8 * q + 4);
            uint4 uw = make_uint4(pkbf16(__expf(pv.x), __expf(pv.y)),
                                  pkbf16(__expf(pv.z), __expf(pv.w)),
                                  pkbf16(__expf(rv.x), __expf(rv.y)),
                                  pkbf16(__expf(rv.z), __expf(rv.w)));
            A[mt][kt] = __builtin_bit_cast(bf16x8, uw);
        }
    }

    const float* ybase = y + ((size_t)b * T_ + (size_t)SEG_ * s) * K_;
    if (tid < K_) yS[0][tid] = __expf(ybase[tid]);   // stage step 0
    __syncthreads();

    const int L = lenS[0] + lenS[1] + lenS[2] + lenS[3];
    int ns = L - SEG_ * s;
    ns = ns < 0 ? 0 : (ns > SEG_ ? SEG_ : ns);

    float c_acc = 0.0f;
    int cur = 0;

    for (int tt = 0; tt < ns; ++tt) {
        // issue next y-row load early (written to LDS late; T14 split)
        float ynext = 0.0f;
        const bool hasn = (tt + 1 < ns);
        if (hasn && tid < K_) ynext = ybase[(tt + 1) * K_ + tid];

        // B-frags from shared block: (kt,nt): rows 32kt+8q+j, col 32u+16nt+ci
        const char* rb = (const char*)&Mb[u][cur][0];
        bf16x8 Bf[4][2];
        #pragma unroll
        for (int kt = 0; kt < 4; ++kt) {
            #pragma unroll
            for (int nt = 0; nt < 2; ++nt)
                Bf[kt][nt] = *(const bf16x8*)(rb + ((kt * 4 + q) * 32 + 16 * nt + ci) * 16);
        }

        // renorm: consume pair-summed partial published at tt-1
        float rinv = 1.0f;
        if (tt && (tt & 3) == 0) {
            const float S = wsumS[u][0] + wsumS[u][1];
            rinv = __builtin_amdgcn_rcpf(S);
            c_acc += __logf(S);
        }
        const bool pub = ((tt & 3) == 3);
        const int ycur = tt & 1;

        char* wb = (char*)&Mb[u][cur ^ 1][0];
        float spart = 0.0f;
        #pragma unroll
        for (int mt = 0; mt < 4; ++mt) {
            f32x4 C0 = {0.f, 0.f, 0.f, 0.f}, C1 = {0.f, 0.f, 0.f, 0.f};
            #pragma unroll
            for (int kt = 0; kt < 4; ++kt) {
                C0 = __builtin_amdgcn_mfma_f32_16x16x32_bf16(A[mt][kt], Bf[kt][0], C0, 0, 0, 0);
                C1 = __builtin_amdgcn_mfma_f32_16x16x32_bf16(A[mt][kt], Bf[kt][1], C1, 0, 0, 0);
            }
            // ey for rows 64e+16mt+4q..+4 (staged, already exp'd)
            f32x4 ev = *(const f32x4*)&yS[ycur][64 * e + 16 * mt + 4 * q];
            ev *= rinv;
            C0 *= ev; C1 *= ev;
            if (pub)
                spart += (C0.x + C0.y) + (C0.z + C0.w)
                       + (C1.x + C1.y) + (C1.z + C1.w);
            // write rows 64e+16mt+4q+r: g'=8e+2mt+(q>>1), byte off 8(q&1)
            const int gp = 8 * e + 2 * mt + (q >> 1);
            const int bo = 8 * (q & 1);
            uint2 d0 = make_uint2(pkbf16(C0.x, C0.y), pkbf16(C0.z, C0.w));
            uint2 d1 = make_uint2(pkbf16(C1.x, C1.y), pkbf16(C1.z, C1.w));
            *(uint2*)(wb + (gp * 32 + ci) * 16 + bo)      = d0;
            *(uint2*)(wb + (gp * 32 + 16 + ci) * 16 + bo) = d1;
        }

        if (pub) {                           // publish half-block sum
            spart += __shfl_xor(spart, 1);  spart += __shfl_xor(spart, 2);
            spart += __shfl_xor(spart, 4);  spart += __shfl_xor(spart, 8);
            spart += __shfl_xor(spart, 16); spart += __shfl_xor(spart, 32);
            if (lane == 0) wsumS[u][e] = spart;
        }
        if (hasn && tid < K_) yS[ycur ^ 1][tid] = __expf(ynext);

        __syncthreads();
        cur ^= 1;
    }

    // ---- epilogue: cols [32u+16e, 32u+16e+16) -> global [c][i] ----
    unsigned short* gout = Mout + ((size_t)bs << 14);
    const char* rb = (const char*)&Mb[u][cur][0];
    #pragma unroll
    for (int p = 0; p < 4; ++p) {
        const int lc = 16 * e + 4 * p + (lane >> 4);
        const int g  = lane & 15;
        uint4 v4 = *(const uint4*)(rb + (g * 32 + lc) * 16);
        *(uint4*)((char*)gout + (((32 * u + lc) << 7) + 8 * g) * 2) = v4;
    }
    if (lane == 0 && e == 0) Cout[bs * 4 + u] = c_acc;
}

// ---------------------------------------------------------------------------
// Phase 2: combine. One block per batch. Thread (cg,ig) owns c in [8cg,8cg+8),
// i in [8ig,8ig+8). Matrix chunks prefetched from global into ping-pong reg
// banks (static indexing), vectorized bf16 unpack + FMA, two-pass LDS reduce.
// Per-col-block scales folded into u before each matvec. (Unchanged, proven.)
// ---------------------------------------------------------------------------
__global__ __launch_bounds__(256) void crf_comb_kernel(
    const unsigned short* __restrict__ Mseg,
    const float* __restrict__ Cseg,      // [B*S][4]
    float* __restrict__ out)
{
    const int b   = blockIdx.x;
    const int tid = threadIdx.x;
    const int cg  = tid >> 4;
    const int ig  = tid & 15;

    __shared__ float uSc[K_];
    __shared__ __align__(16) float tmp[16][K_];
    __shared__ float redS[4];

    if (tid < K_) uSc[tid] = (tid == 2) ? 1.0f : 0.0f;   // e_SOS

    float c_tot = 0.0f;
    uint4 RA[8], RB[8];
    {
        const unsigned short* M0 = Mseg + ((size_t)(b * S_) << 14);
        #pragma unroll
        for (int r = 0; r < 8; ++r)
            RA[r] = *(const uint4*)(M0 + ((8 * cg + r) << 7) + 8 * ig);
    }
    __syncthreads();

    #pragma unroll
    for (int s = 0; s < S_; ++s) {
        const uint4* Rcur = (s & 1) ? RB : RA;           // s is compile-time
        uint4*       Rnxt = (s & 1) ? RA : RB;
        if (s + 1 < S_) {
            const unsigned short* Mn = Mseg + ((size_t)(b * S_ + s + 1) << 14);
            #pragma unroll
            for (int r = 0; r < 8; ++r)
                Rnxt[r] = *(const uint4*)(Mn + ((8 * cg + r) << 7) + 8 * ig);
        }

        const float g0 = Cseg[(b * S_ + s) * 4 + 0];
        const float g1 = Cseg[(b * S_ + s) * 4 + 1];
        const float g2 = Cseg[(b * S_ + s) * 4 + 2];
        const float g3 = Cseg[(b * S_ + s) * 4 + 3];
        const float cmax = fmaxf(fmaxf(g0, g1), fmaxf(g2, g3));
        const float gw = (cg < 8) ? ((cg < 4) ? g0 : g1) : ((cg < 12) ? g2 : g3);
        const float fw = __expf(gw - cmax);

        float acc[8];
        #pragma unroll
        for (int e = 0; e < 8; ++e) acc[e] = 0.0f;
        #pragma unroll
        for (int r = 0; r < 8; ++r) {
            const float ub = uSc[8 * cg + r] * fw;
            const uint4 m4 = Rcur[r];
            const unsigned int* mw_ = (const unsigned int*)&m4;
            #pragma unroll
            for (int h2 = 0; h2 < 4; ++h2) {
                const unsigned int uu = mw_[h2];
                acc[2 * h2]     += __builtin_bit_cast(float, uu << 16) * ub;
                acc[2 * h2 + 1] += __builtin_bit_cast(float, uu & 0xFFFF0000u) * ub;
            }
        }
        *(f32x4*)&tmp[cg][8 * ig]     = *(const f32x4*)&acc[0];
        *(f32x4*)&tmp[cg][8 * ig + 4] = *(const f32x4*)&acc[4];
        __syncthreads();

        float un = 0.0f;
        if (tid < K_) {
            #pragma unroll
            for (int c2 = 0; c2 < 16; ++c2) un += tmp[c2][tid];
        }
        float ps = un;
        ps += __shfl_xor(ps, 1);  ps += __shfl_xor(ps, 2);
        ps += __shfl_xor(ps, 4);  ps += __shfl_xor(ps, 8);
        ps += __shfl_xor(ps, 16); ps += __shfl_xor(ps, 32);
        if ((tid & 63) == 0) redS[tid >> 6] = ps;
        __syncthreads();
        const float total = (redS[0] + redS[1]) + (redS[2] + redS[3]);
        const float rt = 1.0f / total;
        if (tid < K_) uSc[tid] = un * rt;
        c_tot += __logf(total) + cmax;
        __syncthreads();
    }

    if (tid == 0) out[b] = c_tot;
}

extern "C" void kernel_launch(void* const* d_in, const int* in_sizes, int n_in,
                              void* d_out, int out_size, void* d_ws, size_t ws_size,
                              hipStream_t stream) {
    const float* y     = (const float*)d_in[0];   // (B, T, K) fp32
    const float* mask  = (const float*)d_in[1];   // (B, T)    fp32 0/1
    const float* trans = (const float*)d_in[2];   // (K, K)    fp32
    float* out = (float*)d_out;                   // (B,)      fp32

    unsigned short* Mws = (unsigned short*)d_ws;                       // 16.78 MB
    float* Cws = (float*)((char*)d_ws + (size_t)B_ * S_ * K_ * K_ * 2);

    crf_seg_kernel<<<B_ * S_, 512, 0, stream>>>(y, mask, trans, Mws, Cws);
    crf_comb_kernel<<<B_, 256, 0, stream>>>(Mws, Cws, out);
}

// Round 6
// 168.464 us; speedup vs baseline: 1.2020x; 1.1486x over previous
//
#include <hip/hip_runtime.h>
#include <math.h>

#define B_ 64
#define T_ 256
#define K_ 128
#define S_ 8
#define SEG_ 32

typedef float f32x4 __attribute__((ext_vector_type(4)));
typedef short bf16x8 __attribute__((ext_vector_type(8)));

static __device__ __forceinline__ unsigned int bf16rne(float x) {
    unsigned int u = __builtin_bit_cast(unsigned int, x);
    return (u + 0x7FFFu + ((u >> 16) & 1u)) >> 16;
}
static __device__ __forceinline__ unsigned int pkbf16(float a, float b) {
    return bf16rne(a) | (bf16rne(b) << 16);
}

// ---------------------------------------------------------------------------
// Phase 1: per-(batch,segment) transfer matrix M_s = prod diag(ey_t)*Texp.
// Block = 128 threads (2 waves) owns a 16-COLUMN panel of M; wave e computes
// output rows [64e,64e+64) (A = 64 rows of Texp, 64 regs -> AGPR file).
// Grid = B*S*8 panels = 4096 blocks -> ~8 independent blocks/CU at different
// loop phases (TLP hides the per-step latency chain that serialized R5).
// Panel in LDS col-major, XOR-swizzled: elem(col,row) at byte
//   col*256 + ((slot ^ col)<<4) + (row&7)*2, slot=row>>3  (conflict-free).
// Per step per wave: 4 ds_read_b128 (B), 16 MFMA, 4 ds_write_b64, 1 exp.
// ey staged per-wave into LDS (1 exp per row, x16 dedup vs R5), rinv folded.
// Renorm every 4 steps; per-panel log-scale -> Cout[bs][pan].
// blockIdx mapped as (pan = blk>>9, bs = blk&511) so the 8 panels of one
// (b,s) share an XCD L2 for y reads.
// bf16 pack = software RNE pkbf16 (proven; inline-asm cvt_pk NaN'd in R3).
// ---------------------------------------------------------------------------
__global__ __launch_bounds__(128) void crf_seg_kernel(
    const float* __restrict__ y,
    const float* __restrict__ mask,
    const float* __restrict__ trans,
    unsigned short* __restrict__ Mout,   // [B*S][128 col][128 row] bf16
    float* __restrict__ Cout)            // [B*S][8] per-panel log-scales
{
    const int blk  = blockIdx.x;
    const int pan  = blk >> 9;      // 0..7  (panel: cols [16pan,16pan+16))
    const int bs   = blk & 511;
    const int b    = bs >> 3;
    const int s    = bs & 7;
    const int tid  = threadIdx.x;   // 0..127
    const int e    = tid >> 6;      // wave 0/1 = row half
    const int lane = tid & 63;
    const int q    = lane >> 4;
    const int ci   = lane & 15;

    __shared__ __align__(16) unsigned short Mp[2][16 * K_];  // 8 KB dbuf
    __shared__ __align__(16) float yE[K_];                   // scaled exp(y) row
    __shared__ float wsumS[2];
    __shared__ int lenS[4];

    // ---- sequence length (mask is a contiguous 1.0 prefix) ----
    {
        float m0 = mask[b * T_ + tid];
        float m1 = mask[b * T_ + 128 + tid];
        unsigned long long b0 = __ballot(m0 != 0.0f);
        unsigned long long b1 = __ballot(m1 != 0.0f);
        if (lane == 0) { lenS[e] = __popcll(b0); lenS[2 + e] = __popcll(b1); }
    }

    // ---- identity panel into buf 0 (swizzled): col gc has 1.0 at row gc ----
    #pragma unroll
    for (int p = 0; p < 2; ++p) {
        const int it = p * 128 + tid;        // 0..255 -> (lc, slot j)
        const int lc = it >> 4;
        const int j  = it & 15;
        const int gc = 16 * pan + lc;
        uint4 u4 = make_uint4(0u, 0u, 0u, 0u);
        if ((gc >> 3) == j) {
            const int d = gc & 7;
            ((unsigned int*)&u4)[d >> 1] = (d & 1) ? 0x3F800000u : 0x00003F80u;
        }
        *(uint4*)((char*)&Mp[0][0] + lc * 256 + ((j ^ lc) << 4)) = u4;
    }

    // ---- A-frags: Texp rows [64e,64e+64): rows 64e+16mt+ci, A[m=ci][k=8q+j]
    bf16x8 A[4][4];
    #pragma unroll
    for (int mt = 0; mt < 4; ++mt) {
        const float* tp = trans + (64 * e + 16 * mt + ci) * K_;
        #pragma unroll
        for (int kt = 0; kt < 4; ++kt) {
            f32x4 pv = *(const f32x4*)(tp + 32 * kt + 8 * q);
            f32x4 rv = *(const f32x4*)(tp + 32 * kt + 8 * q + 4);
            uint4 uw = make_uint4(pkbf16(__expf(pv.x), __expf(pv.y)),
                                  pkbf16(__expf(pv.z), __expf(pv.w)),
                                  pkbf16(__expf(rv.x), __expf(rv.y)),
                                  pkbf16(__expf(rv.z), __expf(rv.w)));
            A[mt][kt] = __builtin_bit_cast(bf16x8, uw);
        }
    }

    __syncthreads();
    const int L = lenS[0] + lenS[1] + lenS[2] + lenS[3];
    int ns = L - SEG_ * s;
    ns = ns < 0 ? 0 : (ns > SEG_ ? SEG_ : ns);

    const float* yb = y + ((size_t)b * T_ + (size_t)SEG_ * s) * K_;
    float c_acc = 0.0f;
    int cur = 0;

    for (int tt = 0; tt < ns; ++tt) {
        // own-row y element (global; L2/L1 -- latency hidden by block TLP)
        const float yraw = yb[tt * K_ + 64 * e + lane];

        // B-frags: lane (q,ci) rows 32kt+8q+j, col ci (swizzled col-major)
        const char* rb = (const char*)&Mp[cur][0];
        bf16x8 Bf[4];
        #pragma unroll
        for (int kt = 0; kt < 4; ++kt)
            Bf[kt] = *(const bf16x8*)(rb + ci * 256 + (((4 * kt + q) ^ ci) << 4));

        // renorm: consume partials published at tt-1
        float rinv = 1.0f;
        if (tt && (tt & 3) == 0) {
            const float S = wsumS[0] + wsumS[1];
            rinv = __builtin_amdgcn_rcpf(S);
            c_acc += __logf(S);
        }
        // stage scaled ey for own 64 rows (wave-local: 1 exp per row)
        yE[64 * e + lane] = __expf(yraw) * rinv;

        const bool pub = ((tt & 3) == 3);
        char* wb = (char*)&Mp[cur ^ 1][0];
        float spart = 0.0f;
        #pragma unroll
        for (int mt = 0; mt < 4; ++mt) {
            f32x4 C = {0.f, 0.f, 0.f, 0.f};
            #pragma unroll
            for (int kt = 0; kt < 4; ++kt)
                C = __builtin_amdgcn_mfma_f32_16x16x32_bf16(A[mt][kt], Bf[kt], C, 0, 0, 0);
            // rows 64e+16mt+4q+r, col 16pan+ci
            f32x4 ev = *(const f32x4*)&yE[64 * e + 16 * mt + 4 * q];
            C *= ev;
            if (pub) spart += (C.x + C.y) + (C.z + C.w);
            const int slot = 8 * e + 2 * mt + (q >> 1);
            uint2 d = make_uint2(pkbf16(C.x, C.y), pkbf16(C.z, C.w));
            *(uint2*)(wb + ci * 256 + ((slot ^ ci) << 4) + 8 * (q & 1)) = d;
        }
        if (pub) {
            spart += __shfl_xor(spart, 1);  spart += __shfl_xor(spart, 2);
            spart += __shfl_xor(spart, 4);  spart += __shfl_xor(spart, 8);
            spart += __shfl_xor(spart, 16); spart += __shfl_xor(spart, 32);
            if (lane == 0) wsumS[e] = spart;
        }
        __syncthreads();
        cur ^= 1;
    }

    // ---- epilogue: panel -> global [col][row] (de-swizzled, coalesced) ----
    unsigned short* gout = Mout + ((size_t)bs << 14);
    const char* rb = (const char*)&Mp[cur][0];
    #pragma unroll
    for (int p = 0; p < 2; ++p) {
        const int it = p * 128 + tid;
        const int lc = it >> 4;
        const int j  = it & 15;
        uint4 v4 = *(const uint4*)(rb + lc * 256 + ((j ^ lc) << 4));
        *(uint4*)((char*)gout + ((16 * pan + lc) << 8) + j * 16) = v4;
    }
    if (tid == 0) Cout[bs * 8 + pan] = c_acc;
}

// ---------------------------------------------------------------------------
// Phase 2: combine. One block per batch. Thread (cg,ig) owns c in [8cg,8cg+8),
// i in [8ig,8ig+8). Matrix chunks prefetched from global into ping-pong reg
// banks (static indexing), vectorized bf16 unpack + FMA, two-pass LDS reduce.
// Per-PANEL (16-col) scales folded into u before each matvec.
// ---------------------------------------------------------------------------
__global__ __launch_bounds__(256) void crf_comb_kernel(
    const unsigned short* __restrict__ Mseg,
    const float* __restrict__ Cseg,      // [B*S][8]
    float* __restrict__ out)
{
    const int b   = blockIdx.x;
    const int tid = threadIdx.x;
    const int cg  = tid >> 4;
    const int ig  = tid & 15;

    __shared__ float uSc[K_];
    __shared__ __align__(16) float tmp[16][K_];
    __shared__ float redS[4];

    if (tid < K_) uSc[tid] = (tid == 2) ? 1.0f : 0.0f;   // e_SOS

    float c_tot = 0.0f;
    uint4 RA[8], RB[8];
    {
        const unsigned short* M0 = Mseg + ((size_t)(b * S_) << 14);
        #pragma unroll
        for (int r = 0; r < 8; ++r)
            RA[r] = *(const uint4*)(M0 + ((8 * cg + r) << 7) + 8 * ig);
    }
    __syncthreads();

    #pragma unroll
    for (int s = 0; s < S_; ++s) {
        const uint4* Rcur = (s & 1) ? RB : RA;           // s is compile-time
        uint4*       Rnxt = (s & 1) ? RA : RB;
        if (s + 1 < S_) {
            const unsigned short* Mn = Mseg + ((size_t)(b * S_ + s + 1) << 14);
            #pragma unroll
            for (int r = 0; r < 8; ++r)
                Rnxt[r] = *(const uint4*)(Mn + ((8 * cg + r) << 7) + 8 * ig);
        }

        const float* gp = Cseg + (b * S_ + s) * 8;
        const float g0 = gp[0], g1 = gp[1], g2 = gp[2], g3 = gp[3];
        const float g4 = gp[4], g5 = gp[5], g6 = gp[6], g7 = gp[7];
        const float cmax = fmaxf(fmaxf(fmaxf(g0, g1), fmaxf(g2, g3)),
                                 fmaxf(fmaxf(g4, g5), fmaxf(g6, g7)));
        const int ph = cg >> 1;                          // panel of this c-group
        float gw = g0;
        gw = (ph == 1) ? g1 : gw;  gw = (ph == 2) ? g2 : gw;
        gw = (ph == 3) ? g3 : gw;  gw = (ph == 4) ? g4 : gw;
        gw = (ph == 5) ? g5 : gw;  gw = (ph == 6) ? g6 : gw;
        gw = (ph == 7) ? g7 : gw;
        const float fw = __expf(gw - cmax);

        float acc[8];
        #pragma unroll
        for (int k = 0; k < 8; ++k) acc[k] = 0.0f;
        #pragma unroll
        for (int r = 0; r < 8; ++r) {
            const float ub = uSc[8 * cg + r] * fw;
            const uint4 m4 = Rcur[r];
            const unsigned int* mw_ = (const unsigned int*)&m4;
            #pragma unroll
            for (int h2 = 0; h2 < 4; ++h2) {
                const unsigned int uu = mw_[h2];
                acc[2 * h2]     += __builtin_bit_cast(float, uu << 16) * ub;
                acc[2 * h2 + 1] += __builtin_bit_cast(float, uu & 0xFFFF0000u) * ub;
            }
        }
        *(f32x4*)&tmp[cg][8 * ig]     = *(const f32x4*)&acc[0];
        *(f32x4*)&tmp[cg][8 * ig + 4] = *(const f32x4*)&acc[4];
        __syncthreads();

        float un = 0.0f;
        if (tid < K_) {
            #pragma unroll
            for (int c2 = 0; c2 < 16; ++c2) un += tmp[c2][tid];
        }
        float ps = un;
        ps += __shfl_xor(ps, 1);  ps += __shfl_xor(ps, 2);
        ps += __shfl_xor(ps, 4);  ps += __shfl_xor(ps, 8);
        ps += __shfl_xor(ps, 16); ps += __shfl_xor(ps, 32);
        if ((tid & 63) == 0) redS[tid >> 6] = ps;
        __syncthreads();
        const float total = (redS[0] + redS[1]) + (redS[2] + redS[3]);
        const float rt = 1.0f / total;
        if (tid < K_) uSc[tid] = un * rt;
        c_tot += __logf(total) + cmax;
        __syncthreads();
    }

    if (tid == 0) out[b] = c_tot;
}

extern "C" void kernel_launch(void* const* d_in, const int* in_sizes, int n_in,
                              void* d_out, int out_size, void* d_ws, size_t ws_size,
                              hipStream_t stream) {
    const float* y     = (const float*)d_in[0];   // (B, T, K) fp32
    const float* mask  = (const float*)d_in[1];   // (B, T)    fp32 0/1
    const float* trans = (const float*)d_in[2];   // (K, K)    fp32
    float* out = (float*)d_out;                   // (B,)      fp32

    unsigned short* Mws = (unsigned short*)d_ws;                       // 16.78 MB
    float* Cws = (float*)((char*)d_ws + (size_t)B_ * S_ * K_ * K_ * 2);

    crf_seg_kernel<<<B_ * S_ * 8, 128, 0, stream>>>(y, mask, trans, Mws, Cws);
    crf_comb_kernel<<<B_, 256, 0, stream>>>(Mws, Cws, out);
}

// Round 7
// 111.214 us; speedup vs baseline: 1.8207x; 1.5148x over previous
//
#include <hip/hip_runtime.h>
#include <math.h>

#define B_ 64
#define T_ 256
#define K_ 128

typedef const __attribute__((address_space(1))) void* gas1_t;
typedef __attribute__((address_space(3))) void* las3_t;
typedef float f32x4 __attribute__((ext_vector_type(4)));
typedef short bf16x8 __attribute__((ext_vector_type(8)));

static __device__ __forceinline__ unsigned int bf16rne(float x) {
    unsigned int u = __builtin_bit_cast(unsigned int, x);
    return (u + 0x7FFFu + ((u >> 16) & 1u)) >> 16;
}
static __device__ __forceinline__ unsigned int pkbf16(float a, float b) {
    return bf16rne(a) | (bf16rne(b) << 16);
}

// ---------------------------------------------------------------------------
// Bidirectional matvec chains (half the serial depth of the R0 kernel, same
// proven per-step structure, and 1/64 the FLOPs of the R1-R6 matrix scheme).
//   forward  (dir=0): v_H = prod_{t=H..1} D_t Texp  e_SOS          (H steps)
//   backward (dir=1): z = ey_{L-1}; z <- ey_t (.) Texp^T z, t=L-2..H;
//                     w = Texp^T z                                  (L-H steps)
//   out = c_f + c_b + log(v_H . w)   (combine kernel)
// Per block: 4 waves, wave w owns rows [32w,32w+32): 2 mt x 4 kt = 8 MFMA per
// step; v round-trips through double-buffered LDS (16-lane broadcast reads);
// y staged in 16KB chunks via global_load_lds + pre-exp pass; renorm every 4
// steps via deferred partials (R0-verbatim).
// ---------------------------------------------------------------------------
__global__ __launch_bounds__(256) void crf_chain_kernel(
    const float* __restrict__ y,
    const float* __restrict__ mask,
    const float* __restrict__ trans,
    float* __restrict__ vws,     // [B*2][128] end-state vectors (f32)
    float* __restrict__ cws)     // [B*2]      accumulated log-scales
{
    const int bd   = blockIdx.x;
    const int b    = bd >> 1;
    const int dir  = bd & 1;
    const int tid  = threadIdx.x;
    const int w    = tid >> 6;
    const int lane = tid & 63;
    const int q    = lane >> 4;
    const int ci   = lane & 15;

    __shared__ __align__(16) float eybuf[2][32 * K_];    // 2 x 16 KB y chunks
    __shared__ __align__(16) unsigned short vS[2][K_];   // v double buffer (bf16)
    __shared__ __align__(16) float wsumS[4];             // deferred renorm partials
    __shared__ int lenS[4];

    const float* yb = y + (size_t)b * (T_ * K_);

    // ---- sequence length first (backward staging needs L) ----
    {
        float mval = mask[b * T_ + tid];
        unsigned long long bal = __ballot(mval != 0.0f);
        if (lane == 0) lenS[w] = __popcll(bal);
    }
    __syncthreads();
    const int L = lenS[0] + lenS[1] + lenS[2] + lenS[3];   // in [128, 256]
    const int H = L >> 1;
    const int nch = dir ? ((L - H + 31) >> 5) : ((H + 31) >> 5);

    auto stage = [&](int row0, int buf) {                // 4 global_load_lds/wave
        const float* gp = yb + (size_t)row0 * K_;
        #pragma unroll
        for (int s4 = 0; s4 < 4; ++s4) {
            const int seg = 4 * w + s4;                  // 16 segments x 1 KB
            __builtin_amdgcn_global_load_lds(
                (gas1_t)(gp + seg * 256 + lane * 4),
                (las3_t)(&eybuf[buf][seg * 256]), 16, 0, 0);
        }
    };
    stage(dir ? (L - 32) : 0, 0);

    // ---- A-frags: A[m=ci][k=8q+j] for rows 32w+16mt+ci (R0-proven layout) ----
    // forward: A = Texp (row-major reads); backward: A = Texp^T (strided, once)
    bf16x8 A[2][4];
    if (!dir) {
        #pragma unroll
        for (int mt = 0; mt < 2; ++mt) {
            const float* tp = trans + (32 * w + 16 * mt + ci) * K_;
            #pragma unroll
            for (int kt = 0; kt < 4; ++kt) {
                f32x4 p = *(const f32x4*)(tp + 32 * kt + 8 * q);
                f32x4 r = *(const f32x4*)(tp + 32 * kt + 8 * q + 4);
                uint4 u = make_uint4(pkbf16(__expf(p.x), __expf(p.y)),
                                     pkbf16(__expf(p.z), __expf(p.w)),
                                     pkbf16(__expf(r.x), __expf(r.y)),
                                     pkbf16(__expf(r.z), __expf(r.w)));
                A[mt][kt] = __builtin_bit_cast(bf16x8, u);
            }
        }
    } else {
        #pragma unroll
        for (int mt = 0; mt < 2; ++mt) {
            const int rowm = 32 * w + 16 * mt + ci;
            #pragma unroll
            for (int kt = 0; kt < 4; ++kt) {
                const float* cp = trans + (size_t)(32 * kt + 8 * q) * K_ + rowm;
                float e0 = __expf(cp[0 * K_]), e1 = __expf(cp[1 * K_]);
                float e2 = __expf(cp[2 * K_]), e3 = __expf(cp[3 * K_]);
                float e4 = __expf(cp[4 * K_]), e5 = __expf(cp[5 * K_]);
                float e6 = __expf(cp[6 * K_]), e7 = __expf(cp[7 * K_]);
                uint4 u = make_uint4(pkbf16(e0, e1), pkbf16(e2, e3),
                                     pkbf16(e4, e5), pkbf16(e6, e7));
                A[mt][kt] = __builtin_bit_cast(bf16x8, u);
            }
        }
    }

    // ---- state init: forward = one-hot SOS; backward = ey_{L-1} ----
    if (tid < K_) {
        vS[0][tid] = dir
            ? (unsigned short)bf16rne(__expf(yb[(size_t)(L - 1) * K_ + tid]))
            : (unsigned short)((tid == 2) ? 0x3F80 : 0);
    }

    float c_acc = 0.0f;
    int cur = 0;
    int tstep = 0;

    auto step = [&](const float* eyp) {                  // R0-verbatim step
        const unsigned short* vp = vS[cur];
        bf16x8 Bf[4];
        #pragma unroll
        for (int kt = 0; kt < 4; ++kt)
            Bf[kt] = *(const bf16x8*)&vp[32 * kt + 8 * q];

        f32x4 ey0, ey1;
        if (eyp) {
            ey0 = *(const f32x4*)(eyp + 32 * w + 4 * q);
            ey1 = *(const f32x4*)(eyp + 32 * w + 4 * q + 16);
        } else {
            ey0 = (f32x4){1.f, 1.f, 1.f, 1.f};
            ey1 = ey0;
        }

        f32x4 a0 = {0.f, 0.f, 0.f, 0.f}, a1 = {0.f, 0.f, 0.f, 0.f};
        #pragma unroll
        for (int kt = 0; kt < 4; ++kt) {
            a0 = __builtin_amdgcn_mfma_f32_16x16x32_bf16(A[0][kt], Bf[kt], a0, 0, 0, 0);
            a1 = __builtin_amdgcn_mfma_f32_16x16x32_bf16(A[1][kt], Bf[kt], a1, 0, 0, 0);
        }
        f32x4 w0 = a0 * ey0;
        f32x4 w1 = a1 * ey1;

        if (tstep && (tstep & 3) == 0) {     // consume partials from tstep-1
            f32x4 ws = *(const f32x4*)wsumS;
            float S = (ws.x + ws.y) + (ws.z + ws.w);
            float rinv = __builtin_amdgcn_rcpf(S);
            c_acc += __logf(S);
            w0 *= rinv; w1 *= rinv;
        }
        if ((tstep & 3) == 3) {              // publish partial sums
            f32x4 sv = w0 + w1;
            float sp = (sv.x + sv.y) + (sv.z + sv.w);
            sp += __shfl_xor(sp, 16);
            sp += __shfl_xor(sp, 32);
            if (lane == 0) wsumS[w] = sp;
        }
        if (ci == 0) {                       // 8 x 8B writes per wave
            uint2 d0 = make_uint2(pkbf16(w0.x, w0.y), pkbf16(w0.z, w0.w));
            uint2 d1 = make_uint2(pkbf16(w1.x, w1.y), pkbf16(w1.z, w1.w));
            *(uint2*)&vS[cur ^ 1][32 * w + 4 * q]      = d0;
            *(uint2*)&vS[cur ^ 1][32 * w + 16 + 4 * q] = d1;
        }
        __syncthreads();
        cur ^= 1;
        ++tstep;
    };

    for (int c = 0; c < nch; ++c) {
        if (c + 1 < nch) {                   // prefetch next chunk
            stage(dir ? (L - 32 * (c + 2)) : (32 * (c + 1)), (c + 1) & 1);
            asm volatile("s_waitcnt vmcnt(4)" ::: "memory");   // chunk c done
        } else {
            asm volatile("s_waitcnt vmcnt(0)" ::: "memory");
        }
        __syncthreads();                     // all waves' DMA for chunk c visible
        float* bp = eybuf[c & 1];
        #pragma unroll
        for (int i = 0; i < 4; ++i) {        // pre-exp pass (4096 floats/256 thr)
            f32x4 v4 = *(const f32x4*)(bp + i * 1024 + tid * 4);
            v4.x = __expf(v4.x); v4.y = __expf(v4.y);
            v4.z = __expf(v4.z); v4.w = __expf(v4.w);
            *(f32x4*)(bp + i * 1024 + tid * 4) = v4;
        }
        __syncthreads();

        if (!dir) {                          // rows t = 32c + li, ascending
            const int ns = (H - 32 * c) < 32 ? (H - 32 * c) : 32;
            for (int li = 0; li < ns; ++li) step(bp + li * K_);
        } else {                             // rows t = base + li, descending
            const int base = L - 32 * (c + 1);
            const int ls = (c == 0) ? 30 : 31;          // li=31 of c=0 was init
            int le = H - base; if (le < 0) le = 0;      // stop at t = H
            for (int li = ls; li >= le; --li) step(bp + li * K_);
        }
    }
    if (dir) step(nullptr);                  // final unscaled Texp^T application

    // ---- store end state (bf16 widened to f32) + log-scale ----
    if (tid < K_) {
        unsigned int hv = vS[cur][tid];
        vws[(size_t)bd * K_ + tid] = __builtin_bit_cast(float, hv << 16);
    }
    if (tid == 0) cws[bd] = c_acc;
}

// ---------------------------------------------------------------------------
// Combine: out[b] = c_f + c_b + log( v_H . w )
// ---------------------------------------------------------------------------
__global__ __launch_bounds__(128) void crf_comb_kernel(
    const float* __restrict__ vws,
    const float* __restrict__ cws,
    float* __restrict__ out)
{
    const int b   = blockIdx.x;
    const int tid = threadIdx.x;             // 0..127
    __shared__ float red2[2];

    float p = vws[(size_t)(2 * b) * K_ + tid] * vws[(size_t)(2 * b + 1) * K_ + tid];
    p += __shfl_xor(p, 1);  p += __shfl_xor(p, 2);
    p += __shfl_xor(p, 4);  p += __shfl_xor(p, 8);
    p += __shfl_xor(p, 16); p += __shfl_xor(p, 32);
    if ((tid & 63) == 0) red2[tid >> 6] = p;
    __syncthreads();
    if (tid == 0) out[b] = cws[2 * b] + cws[2 * b + 1] + __logf(red2[0] + red2[1]);
}

extern "C" void kernel_launch(void* const* d_in, const int* in_sizes, int n_in,
                              void* d_out, int out_size, void* d_ws, size_t ws_size,
                              hipStream_t stream) {
    const float* y     = (const float*)d_in[0];   // (B, T, K) fp32
    const float* mask  = (const float*)d_in[1];   // (B, T)    fp32 0/1
    const float* trans = (const float*)d_in[2];   // (K, K)    fp32
    float* out = (float*)d_out;                   // (B,)      fp32

    float* vws = (float*)d_ws;                              // 64 KB
    float* cws = (float*)((char*)d_ws + (size_t)B_ * 2 * K_ * sizeof(float));

    crf_chain_kernel<<<B_ * 2, 256, 0, stream>>>(y, mask, trans, vws, cws);
    crf_comb_kernel<<<B_, 128, 0, stream>>>(vws, cws, out);
}